// Round 8
// baseline (121.040 us; speedup 1.0000x reference)
//
#include <hip/hip_runtime.h>
#include <hip/hip_bf16.h>
#include <cstdint>
#include <cstddef>

// ---------------------------------------------------------------------------
// Mamba block forward, MI355X (gfx950).  Round 8.
// Post-mortem r7: BK=128 hurt (halving iters doubled per-iter cost) ->
// per-iter-overhead theory falsified.  All gemm configs pin at ~46us with
// nothing saturated: waves wait ~95% of each iter on the staged tile, and all
// blocks stall in lockstep (device-wide staging bursts).
// Change: per-block K-iteration ROTATION (block starts at k-slice
// (bx+3*by+5*bz) mod kIters, wraps).  Decorrelates block phases so resident
// blocks cover each other's memory stalls.  BK back to 64 (best measured).
// Everything else: r7 structure (verified __syncthreads gemm, fused scan).
// ---------------------------------------------------------------------------

typedef __attribute__((ext_vector_type(4))) float f32x4;
typedef __attribute__((ext_vector_type(8))) short short8;

#define GLOAD_LDS16(g, l)                                                      \
  __builtin_amdgcn_global_load_lds(                                            \
      (const __attribute__((address_space(1))) void*)(g),                      \
      (__attribute__((address_space(3))) void*)(l), 16, 0, 0)

__device__ __forceinline__ unsigned short f2bf(float f) {
  union { float f; unsigned u; } v; v.f = f;
  unsigned u = v.u;
  unsigned r = (u + 0x7FFFu + ((u >> 16) & 1u)) >> 16;  // round-to-nearest-even
  return (unsigned short)r;
}
__device__ __forceinline__ float bf2f(unsigned short u) {
  union { unsigned u; float f; } v; v.u = ((unsigned)u) << 16;
  return v.f;
}

// ---------------------------------------------------------------------------
// fp32 -> bf16 conversion for 5 arrays (blockIdx.y picks the array)
// ---------------------------------------------------------------------------
__global__ __launch_bounds__(256) void convert_all(
    const float* __restrict__ a0, unsigned short* __restrict__ o0, int n0,
    const float* __restrict__ a1, unsigned short* __restrict__ o1, int n1,
    const float* __restrict__ a2, unsigned short* __restrict__ o2, int n2,
    const float* __restrict__ a3, unsigned short* __restrict__ o3, int n3,
    const float* __restrict__ a4, unsigned short* __restrict__ o4, int n4) {
  const float* a; unsigned short* o; int n;
  switch (blockIdx.y) {
    case 0: a = a0; o = o0; n = n0; break;
    case 1: a = a1; o = o1; n = n1; break;
    case 2: a = a2; o = o2; n = n2; break;
    case 3: a = a3; o = o3; n = n3; break;
    default: a = a4; o = o4; n = n4; break;
  }
  int n4c = n >> 2;
  int stride = gridDim.x * blockDim.x;
  for (int i = blockIdx.x * blockDim.x + threadIdx.x; i < n4c; i += stride) {
    float4 v = ((const float4*)a)[i];
    uint2 p;
    p.x = (unsigned)f2bf(v.x) | ((unsigned)f2bf(v.y) << 16);
    p.y = (unsigned)f2bf(v.z) | ((unsigned)f2bf(v.w) << 16);
    ((uint2*)o)[i] = p;
  }
}

// ---------------------------------------------------------------------------
// 64x64-tile bf16 GEMM, C = A @ B^T.  4 waves, 2x2 frags each, BK=64.
// Verified __syncthreads structure + per-block K-rotation: block starts at
// k-slice rot and wraps (fp32 acc is order-independent).  XOR swizzle on 16B
// k-slots (inverse on global source, forward on ds_read).  XCD-chunked
// bijective block swizzle.  OBF: write C bf16.  SPLITK>1: partials at
// C + z*M*N.  Requires M%64==0, N%64==0, (K/SPLITK)%64==0 and kIters pow2.
// ---------------------------------------------------------------------------
template <int SPLITK, int OBF>
__global__ __launch_bounds__(256) void gemm64(
    const unsigned short* __restrict__ A, const unsigned short* __restrict__ B,
    void* __restrict__ Cv, int M, int N, int K) {
  __shared__ unsigned short lds[2][2][64 * 64];  // 32KB
  const int tid  = threadIdx.x;
  const int lane = tid & 63;
  const int w    = tid >> 6;

  // bijective XCD-chunked swizzle (requires gridDim.x % 8 == 0)
  const int nx = gridDim.x, ny = gridDim.y;
  int li = (blockIdx.z * ny + blockIdx.y) * nx + blockIdx.x;
  int xcd = li & 7, idx = li >> 3;
  int by = idx % ny;
  int r_ = idx / ny;
  int slab = nx >> 3;
  int bx = xcd * slab + (r_ % slab);
  int bz = r_ / slab;

  const int mBase = by * 64;
  const int nBase = bx * 64;
  const int kLen  = K / SPLITK;
  const int kBase = (SPLITK > 1) ? bz * kLen : 0;
  const int wr = (w >> 1) * 32;
  const int wc = (w & 1) * 32;
  const int wchunk = tid & 192;  // wave-uniform chunk base for gload_lds

  const int kIters = kLen / 64;            // pow2
  const int rot = (bx + by * 3 + bz * 5) & (kIters - 1);  // phase decorrelator

  auto stage = [&](int b, int slice) {     // slice in [0,kIters)
    int k0 = kBase + slice * 64;
    #pragma unroll
    for (int j = 0; j < 2; ++j) {
      int chunk = tid + j * 256;           // 16B chunks of the 64x64 tile
      int row = chunk >> 3;
      int t = chunk & 7;
      int col = (t ^ (row & 7)) * 8;       // inverse swizzle on global source
      GLOAD_LDS16(&A[(size_t)(mBase + row) * K + k0 + col],
                  &lds[b][0][(size_t)(wchunk + j * 256) * 8]);
      GLOAD_LDS16(&B[(size_t)(nBase + row) * K + k0 + col],
                  &lds[b][1][(size_t)(wchunk + j * 256) * 8]);
    }
  };

  f32x4 acc[2][2];
  #pragma unroll
  for (int m = 0; m < 2; ++m)
    #pragma unroll
    for (int n = 0; n < 2; ++n)
      acc[m][n] = (f32x4){0.f, 0.f, 0.f, 0.f};

  stage(0, rot);
  __syncthreads();
  int buf = 0;
  for (int it = 0; it < kIters; ++it) {
    if (it + 1 < kIters) stage(buf ^ 1, (it + 1 + rot) & (kIters - 1));
    short8 af[2][2], bfr[2][2];
    #pragma unroll
    for (int m = 0; m < 2; ++m)
      #pragma unroll
      for (int kk = 0; kk < 2; ++kk) {
        int row = wr + m * 16 + (lane & 15);
        int s = kk * 4 + (lane >> 4);
        af[m][kk] = *(const short8*)&lds[buf][0][row * 64 + ((s ^ (row & 7)) * 8)];
      }
    #pragma unroll
    for (int n = 0; n < 2; ++n)
      #pragma unroll
      for (int kk = 0; kk < 2; ++kk) {
        int row = wc + n * 16 + (lane & 15);
        int s = kk * 4 + (lane >> 4);
        bfr[n][kk] = *(const short8*)&lds[buf][1][row * 64 + ((s ^ (row & 7)) * 8)];
      }
    #pragma unroll
    for (int kk = 0; kk < 2; ++kk)
      #pragma unroll
      for (int m = 0; m < 2; ++m)
        #pragma unroll
        for (int n = 0; n < 2; ++n)
          acc[m][n] = __builtin_amdgcn_mfma_f32_16x16x32_bf16(
              af[m][kk], bfr[n][kk], acc[m][n], 0, 0, 0);
    __syncthreads();  // drains vmcnt(0): prefetch landed; buf reads done
    buf ^= 1;
  }

  if (OBF) {
    unsigned short* Cb = (unsigned short*)Cv;
    #pragma unroll
    for (int m = 0; m < 2; ++m) {
      int row0 = mBase + wr + m * 16 + (lane >> 4) * 4;
      #pragma unroll
      for (int n = 0; n < 2; ++n) {
        int col = nBase + wc + n * 16 + (lane & 15);
        #pragma unroll
        for (int r = 0; r < 4; ++r)
          Cb[(size_t)(row0 + r) * N + col] = f2bf(acc[m][n][r]);
      }
    }
  } else {
    float* Co = (float*)Cv + (SPLITK > 1 ? (size_t)bz * M * N : (size_t)0);
    #pragma unroll
    for (int m = 0; m < 2; ++m) {
      int row0 = mBase + wr + m * 16 + (lane >> 4) * 4;
      #pragma unroll
      for (int n = 0; n < 2; ++n) {
        int col = nBase + wc + n * 16 + (lane & 15);
        #pragma unroll
        for (int r = 0; r < 4; ++r)
          Co[(size_t)(row0 + r) * N + col] = acc[m][n][r];
      }
    }
  }
}

// out = sum of 4 split-K partials, vectorized
__global__ __launch_bounds__(256) void reduce4(
    const float* __restrict__ P, float* __restrict__ out, int n4) {
  int i = blockIdx.x * 256 + threadIdx.x;
  if (i < n4) {
    f32x4 a = ((const f32x4*)P)[i];
    f32x4 b = ((const f32x4*)P)[i + n4];
    f32x4 c = ((const f32x4*)P)[i + 2 * n4];
    f32x4 d = ((const f32x4*)P)[i + 3 * n4];
    ((f32x4*)out)[i] = (a + b) + (c + d);
  }
}

// ---------------------------------------------------------------------------
// causal depthwise conv (width 4) + silu, bf16 in (xz cols 0..2047) -> bf16 xi
// ---------------------------------------------------------------------------
__global__ __launch_bounds__(256) void conv_silu(
    const unsigned short* __restrict__ xz_bf, const float* __restrict__ cw,
    const float* __restrict__ cb, unsigned short* __restrict__ xi_b) {
  int d0 = threadIdx.x * 8;
  int l0 = blockIdx.x * 4;
  float wgt[8][4], bias[8];
  #pragma unroll
  for (int j = 0; j < 8; ++j) {
    float4 t = *(const float4*)&cw[(d0 + j) * 4];
    wgt[j][0] = t.x; wgt[j][1] = t.y; wgt[j][2] = t.z; wgt[j][3] = t.w;
  }
  *(float4*)(bias + 0) = *(const float4*)&cb[d0];
  *(float4*)(bias + 4) = *(const float4*)&cb[d0 + 4];

  short8 rows[7];
  #pragma unroll
  for (int r = 0; r < 7; ++r) {
    int ll = l0 - 3 + r;
    if (ll >= 0)
      rows[r] = *(const short8*)&xz_bf[(size_t)ll * 4096 + d0];
    else
      rows[r] = (short8){0, 0, 0, 0, 0, 0, 0, 0};
  }
  #pragma unroll
  for (int q = 0; q < 4; ++q) {
    short8 outv;
    #pragma unroll
    for (int j = 0; j < 8; ++j) {
      float acc = bias[j];
      #pragma unroll
      for (int k = 0; k < 4; ++k)
        acc = fmaf(bf2f((unsigned short)rows[q + k][j]), wgt[j][k], acc);
      float s = acc / (1.f + __expf(-acc));
      outv[j] = (short)f2bf(s);
    }
    *(short8*)&xi_b[(size_t)(l0 + q) * 2048 + d0] = outv;
  }
}

// ---------------------------------------------------------------------------
// x_dbl = xi @ x_proj_w^T  (M=1024, N=96, K=2048).  4 waves split K, LDS
// reduce.  cols 0..63 -> delta_raw (bf16), 64..79 -> Bm, 80..95 -> Cm (fp32)
// ---------------------------------------------------------------------------
__global__ __launch_bounds__(256) void xproj(
    const unsigned short* __restrict__ xi_b, const unsigned short* __restrict__ xw_b,
    unsigned short* __restrict__ xd_b, float* __restrict__ Bm, float* __restrict__ Cm) {
  __shared__ f32x4 red[4][64];
  int tid = threadIdx.x, lane = tid & 63, w = tid >> 6;
  int mt = blockIdx.x, nt = blockIdx.y;
  int arow = mt * 16 + (lane & 15);
  int brow = nt * 16 + (lane & 15);
  int kg = (lane >> 4) * 8;
  f32x4 acc = (f32x4){0.f, 0.f, 0.f, 0.f};
  for (int k0 = w * 512; k0 < (w + 1) * 512; k0 += 32) {
    short8 a = *(const short8*)&xi_b[(size_t)arow * 2048 + k0 + kg];
    short8 b = *(const short8*)&xw_b[(size_t)brow * 2048 + k0 + kg];
    acc = __builtin_amdgcn_mfma_f32_16x16x32_bf16(a, b, acc, 0, 0, 0);
  }
  red[w][lane] = acc;
  __syncthreads();
  if (w == 0) {
    acc = red[0][lane];
    acc += red[1][lane];
    acc += red[2][lane];
    acc += red[3][lane];
    int ocol = nt * 16 + (lane & 15);
    #pragma unroll
    for (int r = 0; r < 4; ++r) {
      int row = mt * 16 + (lane >> 4) * 4 + r;
      float v = acc[r];
      if (ocol < 64)      xd_b[row * 64 + ocol] = f2bf(v);
      else if (ocol < 80) Bm[row * 16 + (ocol - 64)] = v;
      else                Cm[row * 16 + (ocol - 80)] = v;
    }
  }
}

// ---------------------------------------------------------------------------
// dtproj tile (MFMA) -> ldsD.  Shared by scan_p1 / scan_p3.  One wave.
// ---------------------------------------------------------------------------
__device__ __forceinline__ void dt_tile(
    const unsigned short* __restrict__ xd, const unsigned short* __restrict__ dtw,
    const float* __restrict__ dtb, int c, int dblk, int lane,
    float* __restrict__ ldsD) {
  short8 afr[2][2], bfr4[4][2];
  #pragma unroll
  for (int lt = 0; lt < 2; ++lt)
    #pragma unroll
    for (int kk = 0; kk < 2; ++kk)
      afr[lt][kk] = *(const short8*)
          &xd[(size_t)(c * 32 + lt * 16 + (lane & 15)) * 64 + kk * 32 + (lane >> 4) * 8];
  #pragma unroll
  for (int dt = 0; dt < 4; ++dt)
    #pragma unroll
    for (int kk = 0; kk < 2; ++kk)
      bfr4[dt][kk] = *(const short8*)
          &dtw[(size_t)(dblk * 64 + dt * 16 + (lane & 15)) * 64 + kk * 32 + (lane >> 4) * 8];
  f32x4 acc[2][4];
  #pragma unroll
  for (int lt = 0; lt < 2; ++lt)
    #pragma unroll
    for (int dt = 0; dt < 4; ++dt)
      acc[lt][dt] = (f32x4){0.f, 0.f, 0.f, 0.f};
  #pragma unroll
  for (int kk = 0; kk < 2; ++kk)
    #pragma unroll
    for (int lt = 0; lt < 2; ++lt)
      #pragma unroll
      for (int dt = 0; dt < 4; ++dt)
        acc[lt][dt] = __builtin_amdgcn_mfma_f32_16x16x32_bf16(
            afr[lt][kk], bfr4[dt][kk], acc[lt][dt], 0, 0, 0);
  #pragma unroll
  for (int dt = 0; dt < 4; ++dt) {
    int dl_ = dt * 16 + (lane & 15);
    float bias = dtb[dblk * 64 + dl_];
    #pragma unroll
    for (int lt = 0; lt < 2; ++lt) {
      #pragma unroll
      for (int r = 0; r < 4; ++r) {
        int ll = lt * 16 + (lane >> 4) * 4 + r;
        float v = acc[lt][dt][r] + bias;
        float sp = (v > 20.f) ? v : log1pf(__expf(v));  // softplus
        ldsD[ll * 64 + dl_] = sp;
      }
    }
  }
}

// ---------------------------------------------------------------------------
// Chunked selective scan, 32 chunks x 32 steps.  Block (dblk, c) = 1 wave.
// ---------------------------------------------------------------------------
__global__ __launch_bounds__(64) void scan_p1(
    const unsigned short* __restrict__ xd, const unsigned short* __restrict__ dtw,
    const float* __restrict__ dtb, const unsigned short* __restrict__ xi,
    const float* __restrict__ BmG, const float* __restrict__ Alog,
    float* __restrict__ P, float* __restrict__ S) {
  __shared__ float ldsD[32 * 64];          // delta [t][d]  8KB
  __shared__ unsigned short ldsU[32 * 64]; // u     [t][d]  4KB
  __shared__ float ldsB[32 * 16];          // B     [t][n]  2KB
  const int dblk = blockIdx.x, c = blockIdx.y;
  const int lane = threadIdx.x;
  const int d = dblk * 64 + lane;

  #pragma unroll
  for (int i = 0; i < 8; ++i)
    ldsB[lane + i * 64] = BmG[c * 512 + lane + i * 64];
  #pragma unroll
  for (int i = 0; i < 4; ++i) {   // u tile, 16B chunks
    int chunk = lane + i * 64;
    int row = chunk >> 3, c8 = chunk & 7;
    *(int4*)&ldsU[row * 64 + c8 * 8] =
        *(const int4*)&xi[(size_t)(c * 32 + row) * 2048 + dblk * 64 + c8 * 8];
  }
  dt_tile(xd, dtw, dtb, c, dblk, lane, ldsD);
  __syncthreads();

  float a[16], p[16], s[16];
  #pragma unroll
  for (int n = 0; n < 16; ++n) {
    a[n] = -__expf(Alog[d * 16 + n]);
    p[n] = 1.f; s[n] = 0.f;
  }
  for (int t = 0; t < 32; ++t) {
    float dl = ldsD[t * 64 + lane];
    float u  = bf2f(ldsU[t * 64 + lane]);
    float du = dl * u;
    float bv[16];
    *(float4*)(bv + 0)  = *(const float4*)&ldsB[t * 16 + 0];
    *(float4*)(bv + 4)  = *(const float4*)&ldsB[t * 16 + 4];
    *(float4*)(bv + 8)  = *(const float4*)&ldsB[t * 16 + 8];
    *(float4*)(bv + 12) = *(const float4*)&ldsB[t * 16 + 12];
    #pragma unroll
    for (int n = 0; n < 16; ++n) {
      float dA = __expf(dl * a[n]);
      s[n] = fmaf(dA, s[n], du * bv[n]);
      p[n] *= dA;
    }
  }
  #pragma unroll
  for (int n = 0; n < 16; ++n) {
    P[(size_t)(c * 16 + n) * 2048 + d] = p[n];
    S[(size_t)(c * 16 + n) * 2048 + d] = s[n];
  }
}

__global__ __launch_bounds__(256) void scan_p2(
    const float* __restrict__ P, const float* __restrict__ S,
    float* __restrict__ SIn) {
  int idx = blockIdx.x * 256 + threadIdx.x;  // 0..32767 = n*2048+d
  float sin_ = 0.f;
  #pragma unroll 4
  for (int c = 0; c < 32; ++c) {
    SIn[c * 32768 + idx] = sin_;
    sin_ = fmaf(P[c * 32768 + idx], sin_, S[c * 32768 + idx]);
  }
}

__global__ __launch_bounds__(64) void scan_p3(
    const unsigned short* __restrict__ xd, const unsigned short* __restrict__ dtw,
    const float* __restrict__ dtb, const unsigned short* __restrict__ xi,
    const float* __restrict__ BmG, const float* __restrict__ CmG,
    const float* __restrict__ Alog, const float* __restrict__ Dv,
    const float* __restrict__ SIn, const unsigned short* __restrict__ xz,
    unsigned short* __restrict__ y_b) {
  __shared__ float ldsD[32 * 64];
  __shared__ unsigned short ldsU[32 * 64];
  __shared__ unsigned short ldsZ[32 * 64];
  __shared__ float ldsB[32 * 16];
  __shared__ float ldsC[32 * 16];
  const int dblk = blockIdx.x, c = blockIdx.y;
  const int lane = threadIdx.x;
  const int d = dblk * 64 + lane;

  #pragma unroll
  for (int i = 0; i < 8; ++i) {
    ldsB[lane + i * 64] = BmG[c * 512 + lane + i * 64];
    ldsC[lane + i * 64] = CmG[c * 512 + lane + i * 64];
  }
  #pragma unroll
  for (int i = 0; i < 4; ++i) {
    int chunk = lane + i * 64;
    int row = chunk >> 3, c8 = chunk & 7;
    *(int4*)&ldsU[row * 64 + c8 * 8] =
        *(const int4*)&xi[(size_t)(c * 32 + row) * 2048 + dblk * 64 + c8 * 8];
    *(int4*)&ldsZ[row * 64 + c8 * 8] =
        *(const int4*)&xz[(size_t)(c * 32 + row) * 4096 + 2048 + dblk * 64 + c8 * 8];
  }
  dt_tile(xd, dtw, dtb, c, dblk, lane, ldsD);
  __syncthreads();

  float a[16], s[16];
  #pragma unroll
  for (int n = 0; n < 16; ++n) {
    a[n] = -__expf(Alog[d * 16 + n]);
    s[n] = SIn[c * 32768 + n * 2048 + d];
  }
  float Dd = Dv[d];
  for (int t = 0; t < 32; ++t) {
    float dl = ldsD[t * 64 + lane];
    float u  = bf2f(ldsU[t * 64 + lane]);
    float du = dl * u;
    float bv[16], cv[16];
    *(float4*)(bv + 0)  = *(const float4*)&ldsB[t * 16 + 0];
    *(float4*)(bv + 4)  = *(const float4*)&ldsB[t * 16 + 4];
    *(float4*)(bv + 8)  = *(const float4*)&ldsB[t * 16 + 8];
    *(float4*)(bv + 12) = *(const float4*)&ldsB[t * 16 + 12];
    *(float4*)(cv + 0)  = *(const float4*)&ldsC[t * 16 + 0];
    *(float4*)(cv + 4)  = *(const float4*)&ldsC[t * 16 + 4];
    *(float4*)(cv + 8)  = *(const float4*)&ldsC[t * 16 + 8];
    *(float4*)(cv + 12) = *(const float4*)&ldsC[t * 16 + 12];
    float y = 0.f;
    #pragma unroll
    for (int n = 0; n < 16; ++n) {
      float dA = __expf(dl * a[n]);
      s[n] = fmaf(dA, s[n], du * bv[n]);
      y = fmaf(s[n], cv[n], y);
    }
    y = fmaf(u, Dd, y);
    float zz = bf2f(ldsZ[t * 64 + lane]);
    float sig = 1.f / (1.f + __expf(-zz));
    y *= zz * sig;
    y_b[(size_t)(c * 32 + t) * 2048 + d] = f2bf(y);
  }
}

// ---------------------------------------------------------------------------
extern "C" void kernel_launch(void* const* d_in, const int* in_sizes, int n_in,
                              void* d_out, int out_size, void* d_ws, size_t ws_size,
                              hipStream_t stream) {
  const float* x      = (const float*)d_in[0];
  const float* Win    = (const float*)d_in[1];
  const float* convw  = (const float*)d_in[2];
  const float* convb  = (const float*)d_in[3];
  const float* xprojw = (const float*)d_in[4];
  const float* dtw    = (const float*)d_in[5];
  const float* dtb    = (const float*)d_in[6];
  const float* Alog   = (const float*)d_in[7];
  const float* Dv     = (const float*)d_in[8];
  const float* Wout   = (const float*)d_in[9];
  float* out = (float*)d_out;

  char* ws = (char*)d_ws;
  size_t off = 0;
  auto alloc = [&](size_t bytes) -> void* {
    void* p = ws + off;
    off = (off + bytes + 255) & ~(size_t)255;
    return p;
  };
  unsigned short* x_bf    = (unsigned short*)alloc((size_t)1024 * 1024 * 2);
  unsigned short* Win_bf  = (unsigned short*)alloc((size_t)4096 * 1024 * 2);
  unsigned short* Wout_bf = (unsigned short*)alloc((size_t)1024 * 2048 * 2);
  unsigned short* xw_bf   = (unsigned short*)alloc((size_t)96 * 2048 * 2);
  unsigned short* dtw_bf  = (unsigned short*)alloc((size_t)2048 * 64 * 2);
  unsigned short* xz_bf   = (unsigned short*)alloc((size_t)1024 * 4096 * 2);
  unsigned short* xi_bf   = (unsigned short*)alloc((size_t)1024 * 2048 * 2);
  unsigned short* xd_bf   = (unsigned short*)alloc((size_t)1024 * 64 * 2);
  float* Bm               = (float*)alloc((size_t)1024 * 16 * 4);
  float* Cm               = (float*)alloc((size_t)1024 * 16 * 4);
  float* P                = (float*)alloc((size_t)32 * 16 * 2048 * 4);  // 4MB
  float* S                = (float*)alloc((size_t)32 * 16 * 2048 * 4);  // 4MB
  float* SIn              = (float*)alloc((size_t)32 * 16 * 2048 * 4);  // 4MB
  unsigned short* y_bf    = (unsigned short*)alloc((size_t)1024 * 2048 * 2);
  float* part4            = (float*)alloc((size_t)4 * 1024 * 1024 * 4); // 16MB

  convert_all<<<dim3(512, 5), 256, 0, stream>>>(
      x, x_bf, 1024 * 1024,
      Win, Win_bf, 4096 * 1024,
      Wout, Wout_bf, 1024 * 2048,
      xprojw, xw_bf, 96 * 2048,
      dtw, dtw_bf, 2048 * 64);
  gemm64<1, 1><<<dim3(64, 16), 256, 0, stream>>>(x_bf, Win_bf, xz_bf, 1024, 4096, 1024);
  conv_silu<<<dim3(256), 256, 0, stream>>>(xz_bf, convw, convb, xi_bf);
  xproj<<<dim3(64, 6), 256, 0, stream>>>(xi_bf, xw_bf, xd_bf, Bm, Cm);
  scan_p1<<<dim3(32, 32), 64, 0, stream>>>(xd_bf, dtw_bf, dtb, xi_bf, Bm, Alog, P, S);
  scan_p2<<<dim3(128), 256, 0, stream>>>(P, S, SIn);
  scan_p3<<<dim3(32, 32), 64, 0, stream>>>(xd_bf, dtw_bf, dtb, xi_bf, Bm, Cm,
                                           Alog, Dv, SIn, xz_bf, y_bf);
  gemm64<4, 0><<<dim3(16, 16, 4), 256, 0, stream>>>(y_bf, Wout_bf, part4, 1024, 1024, 2048);
  reduce4<<<dim3(1024), 256, 0, stream>>>(part4, out, 262144);
}

// Round 9
// 110.725 us; speedup vs baseline: 1.0932x; 1.0932x over previous
//
#include <hip/hip_runtime.h>
#include <hip/hip_bf16.h>
#include <cstdint>
#include <cstddef>

// ---------------------------------------------------------------------------
// Mamba block forward, MI355X (gfx950).  Round 9.
// Base: exact r3 pipeline (best measured, 109.6us).  Single change:
// gemm64 -> depth-3 counted-vmcnt pipeline (T3/T4):
//   3 LDS buffers; prologue stages tiles 0,1,2 (12 gload_lds/wave in flight);
//   per iter: s_waitcnt vmcnt(8) [own tile landed, 2 ahead in flight] ->
//   s_barrier -> sched_barrier(0) [rule #18: block ds_read hoist above the
//   barrier — this missing fence was r6's race] -> ds_read+MFMA ->
//   sched_barrier(0) -> s_barrier -> sched_barrier(0) -> stage tile it+3
//   into the just-freed buffer.  Tail iters drain vmcnt 4 -> 0.
// Per-wave outstanding 4 -> 12, no per-iter drain: staging throughput ~3x.
// ---------------------------------------------------------------------------

typedef __attribute__((ext_vector_type(4))) float f32x4;
typedef __attribute__((ext_vector_type(8))) short short8;

#define GLOAD_LDS16(g, l)                                                      \
  __builtin_amdgcn_global_load_lds(                                            \
      (const __attribute__((address_space(1))) void*)(g),                      \
      (__attribute__((address_space(3))) void*)(l), 16, 0, 0)

__device__ __forceinline__ unsigned short f2bf(float f) {
  union { float f; unsigned u; } v; v.f = f;
  unsigned u = v.u;
  unsigned r = (u + 0x7FFFu + ((u >> 16) & 1u)) >> 16;  // round-to-nearest-even
  return (unsigned short)r;
}
__device__ __forceinline__ float bf2f(unsigned short u) {
  union { unsigned u; float f; } v; v.u = ((unsigned)u) << 16;
  return v.f;
}

// ---------------------------------------------------------------------------
// fp32 -> bf16 conversion for 5 arrays (blockIdx.y picks the array)
// ---------------------------------------------------------------------------
__global__ __launch_bounds__(256) void convert_all(
    const float* __restrict__ a0, unsigned short* __restrict__ o0, int n0,
    const float* __restrict__ a1, unsigned short* __restrict__ o1, int n1,
    const float* __restrict__ a2, unsigned short* __restrict__ o2, int n2,
    const float* __restrict__ a3, unsigned short* __restrict__ o3, int n3,
    const float* __restrict__ a4, unsigned short* __restrict__ o4, int n4) {
  const float* a; unsigned short* o; int n;
  switch (blockIdx.y) {
    case 0: a = a0; o = o0; n = n0; break;
    case 1: a = a1; o = o1; n = n1; break;
    case 2: a = a2; o = o2; n = n2; break;
    case 3: a = a3; o = o3; n = n3; break;
    default: a = a4; o = o4; n = n4; break;
  }
  int n4c = n >> 2;
  int stride = gridDim.x * blockDim.x;
  for (int i = blockIdx.x * blockDim.x + threadIdx.x; i < n4c; i += stride) {
    float4 v = ((const float4*)a)[i];
    uint2 p;
    p.x = (unsigned)f2bf(v.x) | ((unsigned)f2bf(v.y) << 16);
    p.y = (unsigned)f2bf(v.z) | ((unsigned)f2bf(v.w) << 16);
    ((uint2*)o)[i] = p;
  }
}

// ---------------------------------------------------------------------------
// 64x64-tile bf16 GEMM, C = A @ B^T.  4 waves, 2x2 frags each, BK=64.
// Depth-3 counted-vmcnt pipeline (see header).  XOR swizzle on 16B k-slots
// (inverse on global source, forward on ds_read).  XCD-chunked bijective
// block swizzle.  OBF: write C bf16.  SPLITK>1: partials at C + z*M*N.
// Requires M%64==0, N%64==0, (K/SPLITK)%64==0, kIters>=3, gridDim.x%8==0.
// ---------------------------------------------------------------------------
template <int SPLITK, int OBF>
__global__ __launch_bounds__(256) void gemm64(
    const unsigned short* __restrict__ A, const unsigned short* __restrict__ B,
    void* __restrict__ Cv, int M, int N, int K) {
  __shared__ unsigned short lds[3][2][64 * 64];  // 48KB (3 blocks/CU max)
  const int tid  = threadIdx.x;
  const int lane = tid & 63;
  const int w    = tid >> 6;

  // bijective XCD-chunked swizzle (requires gridDim.x % 8 == 0)
  const int nx = gridDim.x, ny = gridDim.y;
  int li = (blockIdx.z * ny + blockIdx.y) * nx + blockIdx.x;
  int xcd = li & 7, idx = li >> 3;
  int by = idx % ny;
  int r_ = idx / ny;
  int slab = nx >> 3;
  int bx = xcd * slab + (r_ % slab);
  int bz = r_ / slab;

  const int mBase = by * 64;
  const int nBase = bx * 64;
  const int kLen  = K / SPLITK;
  const int kBase = (SPLITK > 1) ? bz * kLen : 0;
  const int wr = (w >> 1) * 32;
  const int wc = (w & 1) * 32;
  const int wchunk = tid & 192;  // wave-uniform chunk base for gload_lds

  auto stage = [&](int b, int k0) {
    // exactly 4 gload_lds per thread (vmcnt accounting depends on this)
    #pragma unroll
    for (int j = 0; j < 2; ++j) {
      int chunk = tid + j * 256;       // 16B chunks of the 64x64 tile
      int row = chunk >> 3;
      int t = chunk & 7;
      int col = (t ^ (row & 7)) * 8;   // inverse swizzle on global source
      GLOAD_LDS16(&A[(size_t)(mBase + row) * K + k0 + col],
                  &lds[b][0][(size_t)(wchunk + j * 256) * 8]);
      GLOAD_LDS16(&B[(size_t)(nBase + row) * K + k0 + col],
                  &lds[b][1][(size_t)(wchunk + j * 256) * 8]);
    }
  };

  f32x4 acc[2][2];
  #pragma unroll
  for (int m = 0; m < 2; ++m)
    #pragma unroll
    for (int n = 0; n < 2; ++n)
      acc[m][n] = (f32x4){0.f, 0.f, 0.f, 0.f};

  const int kIters = kLen / 64;  // >= 3
  stage(0, kBase);
  stage(1, kBase + 64);
  stage(2, kBase + 128);         // 12 loads/wave outstanding

  int buf = 0;
  for (int it = 0; it < kIters; ++it) {
    // wait for own tile only; deeper prefetches stay in flight
    if (it + 2 < kIters)
      asm volatile("s_waitcnt vmcnt(8)" ::: "memory");
    else if (it + 1 < kIters)
      asm volatile("s_waitcnt vmcnt(4)" ::: "memory");
    else
      asm volatile("s_waitcnt vmcnt(0)" ::: "memory");
    __builtin_amdgcn_sched_barrier(0);
    __builtin_amdgcn_s_barrier();      // tile `it` fully in LDS (all waves)
    __builtin_amdgcn_sched_barrier(0); // rule #18: no ds_read hoist above

    short8 af[2][2], bfr[2][2];
    #pragma unroll
    for (int m = 0; m < 2; ++m)
      #pragma unroll
      for (int kk = 0; kk < 2; ++kk) {
        int row = wr + m * 16 + (lane & 15);
        int s = kk * 4 + (lane >> 4);
        af[m][kk] = *(const short8*)&lds[buf][0][row * 64 + ((s ^ (row & 7)) * 8)];
      }
    #pragma unroll
    for (int n = 0; n < 2; ++n)
      #pragma unroll
      for (int kk = 0; kk < 2; ++kk) {
        int row = wc + n * 16 + (lane & 15);
        int s = kk * 4 + (lane >> 4);
        bfr[n][kk] = *(const short8*)&lds[buf][1][row * 64 + ((s ^ (row & 7)) * 8)];
      }
    #pragma unroll
    for (int kk = 0; kk < 2; ++kk)
      #pragma unroll
      for (int m = 0; m < 2; ++m)
        #pragma unroll
        for (int n = 0; n < 2; ++n)
          acc[m][n] = __builtin_amdgcn_mfma_f32_16x16x32_bf16(
              af[m][kk], bfr[n][kk], acc[m][n], 0, 0, 0);

    __builtin_amdgcn_sched_barrier(0); // keep reads above the barrier
    __builtin_amdgcn_s_barrier();      // all waves done reading lds[buf]
    __builtin_amdgcn_sched_barrier(0); // no restage drift above the barrier
    if (it + 3 < kIters) stage(buf, kBase + (it + 3) * 64);
    buf = (buf == 2) ? 0 : buf + 1;
  }

  if (OBF) {
    unsigned short* Cb = (unsigned short*)Cv;
    #pragma unroll
    for (int m = 0; m < 2; ++m) {
      int row0 = mBase + wr + m * 16 + (lane >> 4) * 4;
      #pragma unroll
      for (int n = 0; n < 2; ++n) {
        int col = nBase + wc + n * 16 + (lane & 15);
        #pragma unroll
        for (int r = 0; r < 4; ++r)
          Cb[(size_t)(row0 + r) * N + col] = f2bf(acc[m][n][r]);
      }
    }
  } else {
    float* Co = (float*)Cv + (SPLITK > 1 ? (size_t)bz * M * N : (size_t)0);
    #pragma unroll
    for (int m = 0; m < 2; ++m) {
      int row0 = mBase + wr + m * 16 + (lane >> 4) * 4;
      #pragma unroll
      for (int n = 0; n < 2; ++n) {
        int col = nBase + wc + n * 16 + (lane & 15);
        #pragma unroll
        for (int r = 0; r < 4; ++r)
          Co[(size_t)(row0 + r) * N + col] = acc[m][n][r];
      }
    }
  }
}

// out = partial0 + partial1 (split-K reduce), vectorized
__global__ __launch_bounds__(256) void reduce2(
    const float* __restrict__ P, float* __restrict__ out, int n4) {
  int i = blockIdx.x * 256 + threadIdx.x;
  if (i < n4) {
    f32x4 a = ((const f32x4*)P)[i];
    f32x4 b = ((const f32x4*)P)[i + n4];
    ((f32x4*)out)[i] = a + b;
  }
}

// ---------------------------------------------------------------------------
// causal depthwise conv (width 4) + silu, bf16 in (xz cols 0..2047) -> bf16 xi
// ---------------------------------------------------------------------------
__global__ __launch_bounds__(256) void conv_silu(
    const unsigned short* __restrict__ xz_bf, const float* __restrict__ cw,
    const float* __restrict__ cb, unsigned short* __restrict__ xi_b) {
  int d0 = threadIdx.x * 8;
  int l0 = blockIdx.x * 4;
  float wgt[8][4], bias[8];
  #pragma unroll
  for (int j = 0; j < 8; ++j) {
    float4 t = *(const float4*)&cw[(d0 + j) * 4];
    wgt[j][0] = t.x; wgt[j][1] = t.y; wgt[j][2] = t.z; wgt[j][3] = t.w;
  }
  *(float4*)(bias + 0) = *(const float4*)&cb[d0];
  *(float4*)(bias + 4) = *(const float4*)&cb[d0 + 4];

  short8 rows[7];
  #pragma unroll
  for (int r = 0; r < 7; ++r) {
    int ll = l0 - 3 + r;
    if (ll >= 0)
      rows[r] = *(const short8*)&xz_bf[(size_t)ll * 4096 + d0];
    else
      rows[r] = (short8){0, 0, 0, 0, 0, 0, 0, 0};
  }
  #pragma unroll
  for (int q = 0; q < 4; ++q) {
    short8 outv;
    #pragma unroll
    for (int j = 0; j < 8; ++j) {
      float acc = bias[j];
      #pragma unroll
      for (int k = 0; k < 4; ++k)
        acc = fmaf(bf2f((unsigned short)rows[q + k][j]), wgt[j][k], acc);
      float s = acc / (1.f + __expf(-acc));
      outv[j] = (short)f2bf(s);
    }
    *(short8*)&xi_b[(size_t)(l0 + q) * 2048 + d0] = outv;
  }
}

// ---------------------------------------------------------------------------
// x_dbl = xi @ x_proj_w^T  (M=1024, N=96, K=2048).  4 waves split K, LDS
// reduce.  cols 0..63 -> delta_raw (bf16), 64..79 -> Bm, 80..95 -> Cm (fp32)
// ---------------------------------------------------------------------------
__global__ __launch_bounds__(256) void xproj(
    const unsigned short* __restrict__ xi_b, const unsigned short* __restrict__ xw_b,
    unsigned short* __restrict__ xd_b, float* __restrict__ Bm, float* __restrict__ Cm) {
  __shared__ f32x4 red[4][64];
  int tid = threadIdx.x, lane = tid & 63, w = tid >> 6;
  int mt = blockIdx.x, nt = blockIdx.y;
  int arow = mt * 16 + (lane & 15);
  int brow = nt * 16 + (lane & 15);
  int kg = (lane >> 4) * 8;
  f32x4 acc = (f32x4){0.f, 0.f, 0.f, 0.f};
  for (int k0 = w * 512; k0 < (w + 1) * 512; k0 += 32) {
    short8 a = *(const short8*)&xi_b[(size_t)arow * 2048 + k0 + kg];
    short8 b = *(const short8*)&xw_b[(size_t)brow * 2048 + k0 + kg];
    acc = __builtin_amdgcn_mfma_f32_16x16x32_bf16(a, b, acc, 0, 0, 0);
  }
  red[w][lane] = acc;
  __syncthreads();
  if (w == 0) {
    acc = red[0][lane];
    acc += red[1][lane];
    acc += red[2][lane];
    acc += red[3][lane];
    int ocol = nt * 16 + (lane & 15);
    #pragma unroll
    for (int r = 0; r < 4; ++r) {
      int row = mt * 16 + (lane >> 4) * 4 + r;
      float v = acc[r];
      if (ocol < 64)      xd_b[row * 64 + ocol] = f2bf(v);
      else if (ocol < 80) Bm[row * 16 + (ocol - 64)] = v;
      else                Cm[row * 16 + (ocol - 80)] = v;
    }
  }
}

// ---------------------------------------------------------------------------
// delta = softplus(delta_raw @ dt_proj_w^T + dt_proj_b)  (M=1024,N=2048,K=64)
// ---------------------------------------------------------------------------
__global__ __launch_bounds__(64) void dtproj(
    const unsigned short* __restrict__ xd_b, const unsigned short* __restrict__ dtw_b,
    const float* __restrict__ dtb, float* __restrict__ delta) {
  int lane = threadIdx.x;
  int mt = blockIdx.x, nt = blockIdx.y;
  int arow = mt * 16 + (lane & 15);
  int brow = nt * 16 + (lane & 15);
  int kg = (lane >> 4) * 8;
  f32x4 acc = (f32x4){0.f, 0.f, 0.f, 0.f};
  #pragma unroll
  for (int k0 = 0; k0 < 64; k0 += 32) {
    short8 a = *(const short8*)&xd_b[arow * 64 + k0 + kg];
    short8 b = *(const short8*)&dtw_b[brow * 64 + k0 + kg];
    acc = __builtin_amdgcn_mfma_f32_16x16x32_bf16(a, b, acc, 0, 0, 0);
  }
  int ocol = nt * 16 + (lane & 15);
  float bias = dtb[ocol];
  #pragma unroll
  for (int r = 0; r < 4; ++r) {
    int row = mt * 16 + (lane >> 4) * 4 + r;
    float v = acc[r] + bias;
    float sp = (v > 20.f) ? v : log1pf(__expf(v));  // softplus
    delta[(size_t)row * 2048 + ocol] = sp;
  }
}

// ---------------------------------------------------------------------------
// Chunked selective scan. 32 chunks of 32 timesteps. Lane owns channel d,
// 16 states in registers. P/S/SIn layout: [c][n][d].
// ---------------------------------------------------------------------------
__global__ __launch_bounds__(64) void scan_p1(
    const float* __restrict__ delta, const unsigned short* __restrict__ xi_b,
    const float* __restrict__ Bm, const float* __restrict__ A_log,
    float* __restrict__ P, float* __restrict__ S) {
  int d = blockIdx.x * 64 + threadIdx.x;
  int c = blockIdx.y;
  float a[16], p[16], s[16];
  #pragma unroll
  for (int n = 0; n < 16; ++n) {
    a[n] = -__expf(A_log[d * 16 + n]);
    p[n] = 1.f; s[n] = 0.f;
  }
  for (int tb = 0; tb < 8; ++tb) {
    int l0 = c * 32 + tb * 4;
    float dl[4], uu[4], bv[4][16];
    #pragma unroll
    for (int q = 0; q < 4; ++q) {
      dl[q] = delta[(size_t)(l0 + q) * 2048 + d];
      uu[q] = bf2f(xi_b[(size_t)(l0 + q) * 2048 + d]);
      *(float4*)(bv[q] + 0)  = *(const float4*)&Bm[(l0 + q) * 16 + 0];
      *(float4*)(bv[q] + 4)  = *(const float4*)&Bm[(l0 + q) * 16 + 4];
      *(float4*)(bv[q] + 8)  = *(const float4*)&Bm[(l0 + q) * 16 + 8];
      *(float4*)(bv[q] + 12) = *(const float4*)&Bm[(l0 + q) * 16 + 12];
    }
    #pragma unroll
    for (int q = 0; q < 4; ++q) {
      float du = dl[q] * uu[q];
      #pragma unroll
      for (int n = 0; n < 16; ++n) {
        float dA = __expf(dl[q] * a[n]);
        s[n] = fmaf(dA, s[n], du * bv[q][n]);
        p[n] *= dA;
      }
    }
  }
  #pragma unroll
  for (int n = 0; n < 16; ++n) {
    P[(size_t)(c * 16 + n) * 2048 + d] = p[n];
    S[(size_t)(c * 16 + n) * 2048 + d] = s[n];
  }
}

__global__ __launch_bounds__(256) void scan_p2(
    const float* __restrict__ P, const float* __restrict__ S,
    float* __restrict__ SIn) {
  int idx = blockIdx.x * 256 + threadIdx.x;  // 0..32767 = n*2048+d
  float sin_ = 0.f;
  #pragma unroll 8
  for (int c = 0; c < 32; ++c) {
    SIn[c * 32768 + idx] = sin_;
    sin_ = fmaf(P[c * 32768 + idx], sin_, S[c * 32768 + idx]);
  }
}

__global__ __launch_bounds__(64) void scan_p3(
    const float* __restrict__ delta, const unsigned short* __restrict__ xi_b,
    const float* __restrict__ Bm, const float* __restrict__ Cm,
    const float* __restrict__ A_log, const float* __restrict__ Dv,
    const float* __restrict__ SIn, const unsigned short* __restrict__ xz_bf,
    unsigned short* __restrict__ y_b) {
  int d = blockIdx.x * 64 + threadIdx.x;
  int c = blockIdx.y;
  float a[16], s[16];
  #pragma unroll
  for (int n = 0; n < 16; ++n) {
    a[n] = -__expf(A_log[d * 16 + n]);
    s[n] = SIn[c * 32768 + n * 2048 + d];
  }
  float Dd = Dv[d];
  for (int tb = 0; tb < 16; ++tb) {
    int l0 = c * 32 + tb * 2;
    float dl[2], uu[2], zz[2], bv[2][16], cv[2][16];
    #pragma unroll
    for (int q = 0; q < 2; ++q) {
      int l = l0 + q;
      dl[q] = delta[(size_t)l * 2048 + d];
      uu[q] = bf2f(xi_b[(size_t)l * 2048 + d]);
      zz[q] = bf2f(xz_bf[(size_t)l * 4096 + 2048 + d]);
      *(float4*)(bv[q] + 0)  = *(const float4*)&Bm[l * 16 + 0];
      *(float4*)(bv[q] + 4)  = *(const float4*)&Bm[l * 16 + 4];
      *(float4*)(bv[q] + 8)  = *(const float4*)&Bm[l * 16 + 8];
      *(float4*)(bv[q] + 12) = *(const float4*)&Bm[l * 16 + 12];
      *(float4*)(cv[q] + 0)  = *(const float4*)&Cm[l * 16 + 0];
      *(float4*)(cv[q] + 4)  = *(const float4*)&Cm[l * 16 + 4];
      *(float4*)(cv[q] + 8)  = *(const float4*)&Cm[l * 16 + 8];
      *(float4*)(cv[q] + 12) = *(const float4*)&Cm[l * 16 + 12];
    }
    #pragma unroll
    for (int q = 0; q < 2; ++q) {
      float du = dl[q] * uu[q];
      float y = 0.f;
      #pragma unroll
      for (int n = 0; n < 16; ++n) {
        float dA = __expf(dl[q] * a[n]);
        s[n] = fmaf(dA, s[n], du * bv[q][n]);
        y = fmaf(s[n], cv[q][n], y);
      }
      y = fmaf(uu[q], Dd, y);
      float sig = 1.f / (1.f + __expf(-zz[q]));
      y *= zz[q] * sig;
      y_b[(size_t)(l0 + q) * 2048 + d] = f2bf(y);
    }
  }
}

// ---------------------------------------------------------------------------
extern "C" void kernel_launch(void* const* d_in, const int* in_sizes, int n_in,
                              void* d_out, int out_size, void* d_ws, size_t ws_size,
                              hipStream_t stream) {
  const float* x      = (const float*)d_in[0];
  const float* Win    = (const float*)d_in[1];
  const float* convw  = (const float*)d_in[2];
  const float* convb  = (const float*)d_in[3];
  const float* xprojw = (const float*)d_in[4];
  const float* dtw    = (const float*)d_in[5];
  const float* dtb    = (const float*)d_in[6];
  const float* Alog   = (const float*)d_in[7];
  const float* Dv     = (const float*)d_in[8];
  const float* Wout   = (const float*)d_in[9];
  float* out = (float*)d_out;

  char* ws = (char*)d_ws;
  size_t off = 0;
  auto alloc = [&](size_t bytes) -> void* {
    void* p = ws + off;
    off = (off + bytes + 255) & ~(size_t)255;
    return p;
  };
  unsigned short* x_bf    = (unsigned short*)alloc((size_t)1024 * 1024 * 2);
  unsigned short* Win_bf  = (unsigned short*)alloc((size_t)4096 * 1024 * 2);
  unsigned short* Wout_bf = (unsigned short*)alloc((size_t)1024 * 2048 * 2);
  unsigned short* xw_bf   = (unsigned short*)alloc((size_t)96 * 2048 * 2);
  unsigned short* dtw_bf  = (unsigned short*)alloc((size_t)2048 * 64 * 2);
  unsigned short* xz_bf   = (unsigned short*)alloc((size_t)1024 * 4096 * 2);
  unsigned short* xi_bf   = (unsigned short*)alloc((size_t)1024 * 2048 * 2);
  unsigned short* xd_bf   = (unsigned short*)alloc((size_t)1024 * 64 * 2);
  float* Bm               = (float*)alloc((size_t)1024 * 16 * 4);
  float* Cm               = (float*)alloc((size_t)1024 * 16 * 4);
  float* delta            = (float*)alloc((size_t)1024 * 2048 * 4);
  float* P                = (float*)alloc((size_t)32 * 16 * 2048 * 4);  // 4MB
  float* S                = (float*)alloc((size_t)32 * 16 * 2048 * 4);  // 4MB, contiguous after P
  float* SIn              = (float*)alloc((size_t)32 * 16 * 2048 * 4);
  unsigned short* y_bf    = (unsigned short*)alloc((size_t)1024 * 2048 * 2);
  // P,S dead after scan_p2 -> reused as split-K partials (contiguous 8MB).

  convert_all<<<dim3(512, 5), 256, 0, stream>>>(
      x, x_bf, 1024 * 1024,
      Win, Win_bf, 4096 * 1024,
      Wout, Wout_bf, 1024 * 2048,
      xprojw, xw_bf, 96 * 2048,
      dtw, dtw_bf, 2048 * 64);
  gemm64<1, 1><<<dim3(64, 16), 256, 0, stream>>>(x_bf, Win_bf, xz_bf, 1024, 4096, 1024);
  conv_silu<<<dim3(256), 256, 0, stream>>>(xz_bf, convw, convb, xi_bf);
  xproj<<<dim3(64, 6), 256, 0, stream>>>(xi_bf, xw_bf, xd_bf, Bm, Cm);
  dtproj<<<dim3(64, 128), 64, 0, stream>>>(xd_bf, dtw_bf, dtb, delta);
  scan_p1<<<dim3(32, 32), 64, 0, stream>>>(delta, xi_bf, Bm, Alog, P, S);
  scan_p2<<<dim3(128), 256, 0, stream>>>(P, S, SIn);
  scan_p3<<<dim3(32, 32), 64, 0, stream>>>(delta, xi_bf, Bm, Cm, Alog, Dv, SIn, xz_bf, y_bf);
  gemm64<2, 0><<<dim3(16, 16, 2), 256, 0, stream>>>(y_bf, Wout_bf, P, 1024, 1024, 2048);
  reduce2<<<dim3(1024), 256, 0, stream>>>(P, out, 262144);
}